// Round 2
// baseline (1074.365 us; speedup 1.0000x reference)
//
#include <hip/hip_runtime.h>

// GCN rank-1 collapse + one-pass counting-sort bucket partition (R9).
// R8 post-mortem: scatter 107->67us (cursor-line padding worked); WRITE_SIZE
// unchanged (write-amp = bucket-boundary partial lines, not run length).
// Pipeline is at 16% of memory roofline -> structurally fat. The srcP
// partition + deghist kernel exist ONLY to build two u32 degree histograms.
// R9: compute deg_in/deg_out with fire-and-forget global u32 atomics into
// two L2-resident 2MB arrays, fused into scatter_sort (edge values already
// in registers). Drops: srcP staging (half of scatter's LDS work, 20MB
// write), deghist kernel (60MB read + 20M LDS atomics + 16MB write), pDeg
// 16MBx2 traffic. ~1.3GB of L2 line-touches for the atomics (~37us of L2
// time) overlaps with scatter's existing work.

#define TB 256
#define STB 512
#define BSH 13
#define BNODES 8192
#define MAXNB 64
#define SCH 4096
#define SCH4 (SCH / 4)
#define EPT 8
#define CSTR 16
#define INVB 0xFFFFFFFFu

__global__ void init_kernel(unsigned* __restrict__ curD, float* __restrict__ Xsum,
                            unsigned* __restrict__ degD, unsigned* __restrict__ degS,
                            int NB, unsigned CAP, int G, int Npad) {
    int i = blockIdx.x * TB + threadIdx.x;
    if (i < NB) curD[i * CSTR] = (unsigned)i * CAP;
    if (i < G) Xsum[i] = 0.0f;
    if (i < Npad) { degD[i] = 0u; degS[i] = 0u; }
}

__global__ void scatter_sort_kernel(const int* __restrict__ src, const int* __restrict__ dst,
                                    unsigned* __restrict__ curD,
                                    unsigned* __restrict__ dstP,
                                    unsigned* __restrict__ degD, unsigned* __restrict__ degS,
                                    int NB, int E) {
    __shared__ unsigned cntD[MAXNB];      // counts -> insert cursors
    __shared__ unsigned deltaD[MAXNB];    // globalBase - localExclusive
    __shared__ unsigned totD_s;
    __shared__ unsigned payD[SCH];
    __shared__ unsigned char mapD[SCH];

    int tid = threadIdx.x;
    if (tid < MAXNB) cntD[tid] = 0u;
    __syncthreads();

    unsigned sA[EPT], dA[EPT], bD[EPT];
    int blk = blockIdx.x;
#pragma unroll
    for (int v = 0; v < 2; ++v) {
        int q = blk * SCH4 + v * STB + tid;
        int be = q * 4;
        if (be + 3 < E) {
            int4 s4 = ((const int4*)src)[q];
            int4 d4 = ((const int4*)dst)[q];
            sA[v*4+0] = (unsigned)s4.x; sA[v*4+1] = (unsigned)s4.y;
            sA[v*4+2] = (unsigned)s4.z; sA[v*4+3] = (unsigned)s4.w;
            dA[v*4+0] = (unsigned)d4.x; dA[v*4+1] = (unsigned)d4.y;
            dA[v*4+2] = (unsigned)d4.z; dA[v*4+3] = (unsigned)d4.w;
#pragma unroll
            for (int k = 0; k < 4; ++k) bD[v*4+k] = dA[v*4+k] >> BSH;
        } else {
#pragma unroll
            for (int k = 0; k < 4; ++k) {
                int j = be + k;
                if (j < E) {
                    sA[v*4+k] = (unsigned)src[j];
                    dA[v*4+k] = (unsigned)dst[j];
                    bD[v*4+k] = dA[v*4+k] >> BSH;
                } else {
                    bD[v*4+k] = INVB;
                    sA[v*4+k] = 0u; dA[v*4+k] = 0u;
                }
            }
        }
    }

    // Fire-and-forget degree histograms (L2-resident, non-returning atomics
    // overlap with the LDS staging below).
#pragma unroll
    for (int k = 0; k < EPT; ++k) {
        if (bD[k] != INVB) {
            atomicAdd(&degD[dA[k]], 1u);
            atomicAdd(&degS[sA[k]], 1u);
        }
    }

#pragma unroll
    for (int k = 0; k < EPT; ++k) {
        if (bD[k] != INVB) atomicAdd(&cntD[bD[k]], 1u);
    }
    __syncthreads();

    int wv = tid >> 6, ln = tid & 63;
    if (wv == 0) {
        unsigned x = (ln < NB) ? cntD[ln] : 0u;
        unsigned inc = x;
#pragma unroll
        for (int o = 1; o < 64; o <<= 1) {
            unsigned y = __shfl_up(inc, o, 64);
            if (ln >= o) inc += y;
        }
        unsigned exc = inc - x;
        if (ln < NB) {
            unsigned gb = atomicAdd(&curD[ln * CSTR], x);   // exact reservation, 1 line/bucket
            deltaD[ln] = gb - exc;
            cntD[ln] = exc;                                 // insert cursor
        }
        if (ln == 63) totD_s = inc;
    }
    __syncthreads();

#pragma unroll
    for (int k = 0; k < EPT; ++k) {
        if (bD[k] != INVB) {
            unsigned p = atomicAdd(&cntD[bD[k]], 1u);
            payD[p] = ((dA[k] & (BNODES - 1)) << 19) | sA[k];
            mapD[p] = (unsigned char)bD[k];
        }
    }
    __syncthreads();

    unsigned tD = totD_s;
    for (unsigned i = tid; i < tD; i += STB) {
        unsigned b = mapD[i];
        dstP[deltaD[b] + i] = payD[i];   // delta[b]+i = gBase + (i - exc[b])
    }
}

__global__ void prep_kernel(const unsigned* __restrict__ degD, const unsigned* __restrict__ degS,
                            float* __restrict__ pio, float* __restrict__ h0s,
                            float* __restrict__ isiA, int Npad) {
    int i = blockIdx.x * TB + threadIdx.x;
    if (i >= Npad) return;
    float din = (float)degD[i], dout = (float)degS[i];
    float a  = 1.0f / sqrtf(fmaxf(din, 1.0f));    // inv_sqrt_in
    float bo = 1.0f / sqrtf(fmaxf(dout, 1.0f));   // inv_sqrt_out
    pio[i]  = a * bo;
    h0s[i]  = din * bo;   // invalid pad nodes: din=0 -> 0, contribute nothing
    isiA[i] = a;
}

// Weighted histogram over dstP: h[dst_local] += table[src].
__global__ void wh_kernel(const unsigned* __restrict__ dstP, const unsigned* __restrict__ curD,
                          unsigned CAP, const float* __restrict__ table,
                          float* __restrict__ pOut, int Jlg) {
    __shared__ float h[BNODES];
    for (int t = threadIdx.x; t < BNODES; t += TB) h[t] = 0.0f;
    __syncthreads();
    int b = blockIdx.x >> Jlg;
    int j = blockIdx.x & ((1 << Jlg) - 1);
    unsigned s0 = (unsigned)b * CAP;
    unsigned cD = curD[b * CSTR] - s0;
    unsigned lo = (unsigned)(((unsigned long long)cD * (unsigned)j) >> Jlg);
    unsigned hi = (unsigned)(((unsigned long long)cD * (unsigned)(j + 1)) >> Jlg);
    for (unsigned i = lo + threadIdx.x; i < hi; i += TB) {
        unsigned e = dstP[s0 + i];
        atomicAdd(&h[e >> 19], table[e & 0x7FFFFu]);
    }
    __syncthreads();
    float* row = pOut + (size_t)blockIdx.x * BNODES;
    for (int t = threadIdx.x; t < BNODES; t += TB) row[t] = h[t];
}

__global__ void mid_kernel(const float* __restrict__ pC, const float* __restrict__ pio,
                           float* __restrict__ sarr, int Jlg, int Npad) {
    int i = blockIdx.x * TB + threadIdx.x;
    if (i >= Npad) return;
    int b = i >> BSH, l = i & (BNODES - 1);
    int J = 1 << Jlg;
    float t1 = 0.0f;
    for (int j = 0; j < J; ++j)
        t1 += pC[(size_t)((b << Jlg) + j) * BNODES + l];
    sarr[i] = t1 * pio[i];
}

__global__ void poolfinal_kernel(const float* __restrict__ pT, const float* __restrict__ isiA,
                                 const int* __restrict__ graph_ids,
                                 float* __restrict__ Xsum, int Jlg, int N) {
    int i = blockIdx.x * TB + threadIdx.x;
    bool valid = i < N;
    int ii = valid ? i : (N - 1);
    int b = ii >> BSH, l = ii & (BNODES - 1);
    int J = 1 << Jlg;
    float t2 = 0.0f;
    for (int j = 0; j < J; ++j)
        t2 += pT[(size_t)((b << Jlg) + j) * BNODES + l];
    float x = valid ? t2 * isiA[ii] : 0.0f;
    int g = graph_ids[ii];
    int g0 = __shfl(g, 0, 64);
    bool uniform = __all((!valid) || (g == g0));
    if (uniform) {
#pragma unroll
        for (int off = 32; off >= 1; off >>= 1) x += __shfl_down(x, off, 64);
        if ((threadIdx.x & 63) == 0) atomicAdd(&Xsum[g0], x);
    } else if (valid) {
        atomicAdd(&Xsum[g], x);
    }
}

__global__ void final_kernel(const float* __restrict__ Xsum, const int* __restrict__ graph_ids,
                             const float* __restrict__ W1, const float* __restrict__ W2,
                             const float* __restrict__ Wlast,
                             float* __restrict__ out, int N, int GC) {
    int i = blockIdx.x * TB + threadIdx.x;
    if (i < GC) {
        int g = i >> 3, j = i & 7;
        int lo = 0, hi = N;
        while (lo < hi) { int m = (lo + hi) >> 1; if (graph_ids[m] < g) lo = m + 1; else hi = m; }
        int lo2 = lo, hi2 = N;
        while (lo2 < hi2) { int m = (lo2 + hi2) >> 1; if (graph_ids[m] < g + 1) lo2 = m + 1; else hi2 = m; }
        float c = (float)(lo2 - lo);
        float r = 0.0f;
#pragma unroll
        for (int cc = 0; cc < 8; ++cc) {
            float m = 0.0f;
#pragma unroll
            for (int k = 0; k < 8; ++k) m += fmaxf(W1[k], 0.0f) * W2[k * 8 + cc];
            r += fmaxf(m, 0.0f) * Wlast[cc * 8 + j];
        }
        out[i] = Xsum[g] / fmaxf(c, 1.0f) * r;
    }
}

// ---------------- fallback (atomic) path ----------------

__global__ void fb_deg_kernel(const int* __restrict__ src, const int* __restrict__ dst,
                              float* __restrict__ deg_out, float* __restrict__ deg_in, int E) {
    int i = blockIdx.x * TB + threadIdx.x;
    if (i < E) {
        atomicAdd(&deg_out[src[i]], 1.0f);
        atomicAdd(&deg_in[dst[i]], 1.0f);
    }
}

__global__ void fb_prep_kernel(const float* __restrict__ deg_in, const float* __restrict__ deg_out,
                               float* __restrict__ isi, float* __restrict__ iso,
                               float* __restrict__ h0s, int N) {
    int i = blockIdx.x * TB + threadIdx.x;
    if (i < N) {
        float di = deg_in[i], dn = deg_out[i];
        float a = 1.0f / sqrtf(fmaxf(di, 1.0f));
        float b = 1.0f / sqrtf(fmaxf(dn, 1.0f));
        isi[i] = a; iso[i] = b; h0s[i] = di * b;
    }
}

__global__ void fb_conv_kernel(const int* __restrict__ src, const int* __restrict__ dst,
                               const float* __restrict__ vals, float* __restrict__ t, int E) {
    int i = blockIdx.x * TB + threadIdx.x;
    if (i < E) atomicAdd(&t[dst[i]], vals[src[i]]);
}

__global__ void fb_mid_kernel(const float* __restrict__ agg1, const float* __restrict__ isi,
                              const float* __restrict__ iso, float* __restrict__ s, int N) {
    int i = blockIdx.x * TB + threadIdx.x;
    if (i < N) s[i] = agg1[i] * isi[i] * iso[i];
}

__global__ void fb_pool_kernel(const float* __restrict__ t2, const float* __restrict__ isi,
                               const int* __restrict__ graph_ids,
                               float* __restrict__ Xsum, float* __restrict__ counts, int N) {
    int i = blockIdx.x * TB + threadIdx.x;
    bool valid = i < N;
    int ii = valid ? i : (N - 1);
    float x = valid ? t2[ii] * isi[ii] : 0.0f;
    float cnt = valid ? 1.0f : 0.0f;
    int g = graph_ids[ii];
    int g0 = __shfl(g, 0, 64);
    bool uniform = __all((!valid) || (g == g0));
    if (uniform) {
#pragma unroll
        for (int off = 32; off >= 1; off >>= 1) {
            x += __shfl_down(x, off, 64);
            cnt += __shfl_down(cnt, off, 64);
        }
        if ((threadIdx.x & 63) == 0) { atomicAdd(&Xsum[g0], x); atomicAdd(&counts[g0], cnt); }
    } else if (valid) {
        atomicAdd(&Xsum[g], x); atomicAdd(&counts[g], 1.0f);
    }
}

__global__ void fb_final_kernel(const float* __restrict__ Xsum, const float* __restrict__ counts,
                                const float* __restrict__ W1, const float* __restrict__ W2,
                                const float* __restrict__ Wlast, float* __restrict__ out, int GC) {
    int i = blockIdx.x * TB + threadIdx.x;
    if (i < GC) {
        int g = i >> 3, j = i & 7;
        float r = 0.0f;
#pragma unroll
        for (int c = 0; c < 8; ++c) {
            float m = 0.0f;
#pragma unroll
            for (int k = 0; k < 8; ++k) m += fmaxf(W1[k], 0.0f) * W2[k * 8 + c];
            r += fmaxf(m, 0.0f) * Wlast[c * 8 + j];
        }
        out[i] = Xsum[g] / fmaxf(counts[g], 1.0f) * r;
    }
}

// ---------------- launch ----------------

extern "C" void kernel_launch(void* const* d_in, const int* in_sizes, int n_in,
                              void* d_out, int out_size, void* d_ws, size_t ws_size,
                              hipStream_t stream) {
    const float* W1        = (const float*)d_in[0];
    const float* W2        = (const float*)d_in[1];
    const float* Wlast     = (const float*)d_in[2];
    const int*   src       = (const int*)d_in[3];
    const int*   dst       = (const int*)d_in[4];
    const int*   graph_ids = (const int*)d_in[5];
    float* out = (float*)d_out;

    const int E = in_sizes[3];
    const int N = in_sizes[5];
    const int G = out_size / 8;

    int NB   = (N + BNODES - 1) >> BSH;
    int Npad = NB << BSH;
    int NCH  = (E + SCH - 1) / SCH;
    // Per-bucket capacity: mean + 8192 (~20 sigma for E=10M random), 512-aligned.
    unsigned CAP = (unsigned)(((E / (NB > 0 ? NB : 1)) + 8192 + 511) & ~511);

    // Pick largest J in {8,4,2,1} whose layout fits ws.
    int Jlg = 3;
    size_t req = 0;
    size_t o_dstP, o_curD, o_degD, o_degS, o_part, o_pio, o_h0sar, o_isi, o_Xsum;
    for (;; --Jlg) {
        int J = 1 << Jlg;
        size_t off = 0;
        auto A = [&](size_t bytes) { size_t o = off; off = (off + bytes + 127) & ~(size_t)127; return o; };
        o_dstP  = A((size_t)NB * CAP * 4);
        o_curD  = A((size_t)NB * CSTR * 4);
        o_degD  = A((size_t)Npad * 4);
        o_degS  = A((size_t)Npad * 4);
        o_part  = A((size_t)NB * J * BNODES * 4);  // pC -> pT (aliased)
        o_pio   = A((size_t)Npad * 4);
        o_h0sar = A((size_t)Npad * 4);             // h0s -> sarr (aliased)
        o_isi   = A((size_t)Npad * 4);
        o_Xsum  = A((size_t)G * 4);
        req = off;
        if (req <= ws_size || Jlg == 0) break;
    }

    bool fast = (N <= (1 << 19)) && (NB <= MAXNB) && (ws_size >= req) && (E >= 1);

    char* bp = (char*)d_ws;

    if (fast) {
        unsigned* dstP = (unsigned*)(bp + o_dstP);
        unsigned* curD = (unsigned*)(bp + o_curD);
        unsigned* degD = (unsigned*)(bp + o_degD);
        unsigned* degS = (unsigned*)(bp + o_degS);
        float*    pC   = (float*)(bp + o_part);
        float*    pT   = (float*)(bp + o_part);
        float* pio  = (float*)(bp + o_pio);
        float* h0s  = (float*)(bp + o_h0sar);
        float* sarr = (float*)(bp + o_h0sar);
        float* isiA = (float*)(bp + o_isi);
        float* Xsum = (float*)(bp + o_Xsum);

        int gridNp = (Npad + TB - 1) / TB;
        int gridN  = (N + TB - 1) / TB;
        int J = 1 << Jlg;
        int gridI = (max(max(NB, G), Npad) + TB - 1) / TB;

        init_kernel<<<gridI, TB, 0, stream>>>(curD, Xsum, degD, degS, NB, CAP, G, Npad);
        scatter_sort_kernel<<<NCH, STB, 0, stream>>>(src, dst, curD, dstP, degD, degS, NB, E);
        prep_kernel<<<gridNp, TB, 0, stream>>>(degD, degS, pio, h0s, isiA, Npad);
        wh_kernel<<<NB * J, TB, 0, stream>>>(dstP, curD, CAP, h0s, pC, Jlg);
        mid_kernel<<<gridNp, TB, 0, stream>>>(pC, pio, sarr, Jlg, Npad);
        wh_kernel<<<NB * J, TB, 0, stream>>>(dstP, curD, CAP, sarr, pT, Jlg);
        poolfinal_kernel<<<gridN, TB, 0, stream>>>(pT, isiA, graph_ids, Xsum, Jlg, N);
        final_kernel<<<(out_size + TB - 1) / TB, TB, 0, stream>>>(Xsum, graph_ids,
                                                                  W1, W2, Wlast, out, N, out_size);
    } else {
        float* ws = (float*)d_ws;
        size_t f = 0;
        auto FA = [&](size_t n) { size_t o = f; f += (n + 3) & ~(size_t)3; return o; };
        size_t f_degin  = FA(N);
        size_t f_degout = FA(N);
        size_t f_agg1   = FA(N);
        size_t f_t2     = FA(N);
        size_t f_Xsum   = FA(G);
        size_t f_cnt    = FA(G);
        size_t zf = f;
        size_t f_isi = FA(N);
        size_t f_iso = FA(N);
        size_t f_h0s = FA(N);
        size_t f_s   = FA(N);
        hipMemsetAsync(ws, 0, zf * sizeof(float), stream);
        int gridE = (E + TB - 1) / TB;
        int gridN = (N + TB - 1) / TB;
        int gridO = (out_size + TB - 1) / TB;
        fb_deg_kernel<<<gridE, TB, 0, stream>>>(src, dst, ws + f_degout, ws + f_degin, E);
        fb_prep_kernel<<<gridN, TB, 0, stream>>>(ws + f_degin, ws + f_degout,
                                                 ws + f_isi, ws + f_iso, ws + f_h0s, N);
        fb_conv_kernel<<<gridE, TB, 0, stream>>>(src, dst, ws + f_h0s, ws + f_agg1, E);
        fb_mid_kernel<<<gridN, TB, 0, stream>>>(ws + f_agg1, ws + f_isi, ws + f_iso, ws + f_s, N);
        fb_conv_kernel<<<gridE, TB, 0, stream>>>(src, dst, ws + f_s, ws + f_t2, E);
        fb_pool_kernel<<<gridN, TB, 0, stream>>>(ws + f_t2, ws + f_isi, graph_ids,
                                                 ws + f_Xsum, ws + f_cnt, N);
        fb_final_kernel<<<gridO, TB, 0, stream>>>(ws + f_Xsum, ws + f_cnt, W1, W2, Wlast,
                                                  out, out_size);
    }
}

// Round 3
// 379.574 us; speedup vs baseline: 2.8304x; 2.8304x over previous
//
#include <hip/hip_runtime.h>

// GCN rank-1 collapse + one-pass counting-sort bucket partition (R10).
// R9 post-mortem: fused global deg atomics exploded WRITE_SIZE 75->671MB
// (streaming dstP churned L2; every atomic = miss+fetch+dirty-evict).
// Lesson: global atomics need a quiet L2. Reverted to R8 dual-partition.
// R10 on top of R8: (1) deghist/wh TB 256->512 + J 8->16 (back half was
// ~8-16 waves/CU grid-wide -> latency-bound; double concurrency);
// (2) nontemporal LOADS for last-consumer streams only (src/dst, srcP,
// pDeg, pC, wh2's dstP, pT) so dying data doesn't evict live L2/L3 data;
// no nt-stores (everything written is re-read; dstP wants L3 residency);
// (3) scatter split into 2 dispatches (order-independent reservations) so
// rocprof top-5 reveals the true #2 kernel next round.

#define TB 256
#define DTB 512
#define STB 512
#define BSH 13
#define BNODES 8192
#define MAXNB 64
#define SCH 4096
#define SCH4 (SCH / 4)
#define EPT 8
#define CSTR 16
#define INVB 0xFFFFFFFFu

typedef __attribute__((ext_vector_type(4))) int int4v;

__global__ void init_kernel(unsigned* __restrict__ curD, unsigned* __restrict__ curS,
                            float* __restrict__ Xsum, int NB, unsigned CAP, int G) {
    int i = blockIdx.x * TB + threadIdx.x;
    if (i < NB) { curD[i * CSTR] = (unsigned)i * CAP; curS[i * CSTR] = (unsigned)i * CAP; }
    if (i < G) Xsum[i] = 0.0f;
}

__global__ void scatter_sort_kernel(const int* __restrict__ src, const int* __restrict__ dst,
                                    unsigned* __restrict__ curD, unsigned* __restrict__ curS,
                                    unsigned* __restrict__ dstP, unsigned short* __restrict__ srcP,
                                    int NB, int E, int blk0) {
    __shared__ unsigned cntD[MAXNB], cntS[MAXNB];     // counts -> insert cursors
    __shared__ unsigned deltaD[MAXNB], deltaS[MAXNB]; // globalBase - localExclusive
    __shared__ unsigned totD_s, totS_s;
    __shared__ unsigned payD[SCH];
    __shared__ unsigned short valS[SCH];
    __shared__ unsigned char mapD[SCH], mapS[SCH];

    int tid = threadIdx.x;
    if (tid < MAXNB) { cntD[tid] = 0u; cntS[tid] = 0u; }
    __syncthreads();

    unsigned sA[EPT], dA[EPT], bD[EPT], bS[EPT];
    int blk = blockIdx.x + blk0;
#pragma unroll
    for (int v = 0; v < 2; ++v) {
        int q = blk * SCH4 + v * STB + tid;
        int be = q * 4;
        if (be + 3 < E) {
            int4v s4 = __builtin_nontemporal_load((const int4v*)src + q);
            int4v d4 = __builtin_nontemporal_load((const int4v*)dst + q);
#pragma unroll
            for (int k = 0; k < 4; ++k) {
                sA[v*4+k] = (unsigned)s4[k];
                dA[v*4+k] = (unsigned)d4[k];
                bD[v*4+k] = dA[v*4+k] >> BSH;
                bS[v*4+k] = sA[v*4+k] >> BSH;
            }
        } else {
#pragma unroll
            for (int k = 0; k < 4; ++k) {
                int j = be + k;
                if (j < E) {
                    sA[v*4+k] = (unsigned)src[j];
                    dA[v*4+k] = (unsigned)dst[j];
                    bD[v*4+k] = dA[v*4+k] >> BSH;
                    bS[v*4+k] = sA[v*4+k] >> BSH;
                } else {
                    bD[v*4+k] = INVB; bS[v*4+k] = INVB;
                    sA[v*4+k] = 0u; dA[v*4+k] = 0u;
                }
            }
        }
    }

#pragma unroll
    for (int k = 0; k < EPT; ++k) {
        if (bD[k] != INVB) {
            atomicAdd(&cntD[bD[k]], 1u);
            atomicAdd(&cntS[bS[k]], 1u);
        }
    }
    __syncthreads();

    int wv = tid >> 6, ln = tid & 63;
    if (wv == 0) {
        unsigned x = (ln < NB) ? cntD[ln] : 0u;
        unsigned inc = x;
#pragma unroll
        for (int o = 1; o < 64; o <<= 1) {
            unsigned y = __shfl_up(inc, o, 64);
            if (ln >= o) inc += y;
        }
        unsigned exc = inc - x;
        if (ln < NB) {
            unsigned gb = atomicAdd(&curD[ln * CSTR], x);   // exact reservation, 1 line/bucket
            deltaD[ln] = gb - exc;
            cntD[ln] = exc;                                 // insert cursor
        }
        if (ln == 63) totD_s = inc;
    } else if (wv == 1) {
        unsigned x = (ln < NB) ? cntS[ln] : 0u;
        unsigned inc = x;
#pragma unroll
        for (int o = 1; o < 64; o <<= 1) {
            unsigned y = __shfl_up(inc, o, 64);
            if (ln >= o) inc += y;
        }
        unsigned exc = inc - x;
        if (ln < NB) {
            unsigned gb = atomicAdd(&curS[ln * CSTR], x);
            deltaS[ln] = gb - exc;
            cntS[ln] = exc;
        }
        if (ln == 63) totS_s = inc;
    }
    __syncthreads();

#pragma unroll
    for (int k = 0; k < EPT; ++k) {
        if (bD[k] != INVB) {
            unsigned p = atomicAdd(&cntD[bD[k]], 1u);
            payD[p] = ((dA[k] & (BNODES - 1)) << 19) | sA[k];
            mapD[p] = (unsigned char)bD[k];
            unsigned p2 = atomicAdd(&cntS[bS[k]], 1u);
            valS[p2] = (unsigned short)(sA[k] & (BNODES - 1));
            mapS[p2] = (unsigned char)bS[k];
        }
    }
    __syncthreads();

    unsigned tD = totD_s, tS = totS_s;
    for (unsigned i = tid; i < tD; i += STB) {
        unsigned b = mapD[i];
        dstP[deltaD[b] + i] = payD[i];   // delta[b]+i = gBase + (i - exc[b])
    }
    for (unsigned i = tid; i < tS; i += STB) {
        unsigned b = mapS[i];
        srcP[deltaS[b] + i] = valS[i];
    }
}

// Packed degrees per sub-block: high16 = deg_in (dstP), low16 = deg_out (srcP).
__global__ void deghist_kernel(const unsigned short* __restrict__ srcP, const unsigned* __restrict__ dstP,
                               const unsigned* __restrict__ curS, const unsigned* __restrict__ curD,
                               unsigned CAP, unsigned* __restrict__ pDeg, int Jlg) {
    __shared__ unsigned h[BNODES];
    for (int t = threadIdx.x; t < BNODES; t += DTB) h[t] = 0u;
    __syncthreads();
    int b = blockIdx.x >> Jlg;
    int j = blockIdx.x & ((1 << Jlg) - 1);
    unsigned s0 = (unsigned)b * CAP;
    unsigned cD = curD[b * CSTR] - s0;
    unsigned lo = (unsigned)(((unsigned long long)cD * (unsigned)j) >> Jlg);
    unsigned hi = (unsigned)(((unsigned long long)cD * (unsigned)(j + 1)) >> Jlg);
    for (unsigned i = lo + threadIdx.x; i < hi; i += DTB)
        atomicAdd(&h[dstP[s0 + i] >> 19], 0x10000u);
    unsigned cS = curS[b * CSTR] - s0;
    lo = (unsigned)(((unsigned long long)cS * (unsigned)j) >> Jlg);
    hi = (unsigned)(((unsigned long long)cS * (unsigned)(j + 1)) >> Jlg);
    for (unsigned i = lo + threadIdx.x; i < hi; i += DTB)
        atomicAdd(&h[__builtin_nontemporal_load(&srcP[s0 + i])], 1u);
    __syncthreads();
    unsigned* row = pDeg + (size_t)blockIdx.x * BNODES;
    for (int t = threadIdx.x; t < BNODES; t += DTB) row[t] = h[t];
}

__global__ void prep_kernel(const unsigned* __restrict__ pDeg,
                            float* __restrict__ pio, float* __restrict__ h0s,
                            float* __restrict__ isiA, int Jlg, int Npad) {
    int i = blockIdx.x * TB + threadIdx.x;
    if (i >= Npad) return;
    int b = i >> BSH, l = i & (BNODES - 1);
    int J = 1 << Jlg;
    unsigned sum = 0;
    for (int j = 0; j < J; ++j)
        sum += __builtin_nontemporal_load(&pDeg[(size_t)((b << Jlg) + j) * BNODES + l]);
    float din = (float)(sum >> 16), dout = (float)(sum & 0xFFFFu);
    float a  = 1.0f / sqrtf(fmaxf(din, 1.0f));    // inv_sqrt_in
    float bo = 1.0f / sqrtf(fmaxf(dout, 1.0f));   // inv_sqrt_out
    pio[i]  = a * bo;
    h0s[i]  = din * bo;   // invalid pad nodes: din=0 -> 0, contribute nothing
    isiA[i] = a;
}

// Weighted histogram over dstP: h[dst_local] += table[src].
// LAST=1 marks the final consumer of dstP (nt-load).
template <int LAST>
__global__ void wh_kernel(const unsigned* __restrict__ dstP, const unsigned* __restrict__ curD,
                          unsigned CAP, const float* __restrict__ table,
                          float* __restrict__ pOut, int Jlg) {
    __shared__ float h[BNODES];
    for (int t = threadIdx.x; t < BNODES; t += DTB) h[t] = 0.0f;
    __syncthreads();
    int b = blockIdx.x >> Jlg;
    int j = blockIdx.x & ((1 << Jlg) - 1);
    unsigned s0 = (unsigned)b * CAP;
    unsigned cD = curD[b * CSTR] - s0;
    unsigned lo = (unsigned)(((unsigned long long)cD * (unsigned)j) >> Jlg);
    unsigned hi = (unsigned)(((unsigned long long)cD * (unsigned)(j + 1)) >> Jlg);
    for (unsigned i = lo + threadIdx.x; i < hi; i += DTB) {
        unsigned e = LAST ? __builtin_nontemporal_load(&dstP[s0 + i]) : dstP[s0 + i];
        atomicAdd(&h[e >> 19], table[e & 0x7FFFFu]);
    }
    __syncthreads();
    float* row = pOut + (size_t)blockIdx.x * BNODES;
    for (int t = threadIdx.x; t < BNODES; t += DTB) row[t] = h[t];
}

__global__ void mid_kernel(const float* __restrict__ pC, const float* __restrict__ pio,
                           float* __restrict__ sarr, int Jlg, int Npad) {
    int i = blockIdx.x * TB + threadIdx.x;
    if (i >= Npad) return;
    int b = i >> BSH, l = i & (BNODES - 1);
    int J = 1 << Jlg;
    float t1 = 0.0f;
    for (int j = 0; j < J; ++j)
        t1 += __builtin_nontemporal_load(&pC[(size_t)((b << Jlg) + j) * BNODES + l]);
    sarr[i] = t1 * pio[i];   // normal store: sarr is wh2's random-read table, keep cached
}

__global__ void poolfinal_kernel(const float* __restrict__ pT, const float* __restrict__ isiA,
                                 const int* __restrict__ graph_ids,
                                 float* __restrict__ Xsum, int Jlg, int N) {
    int i = blockIdx.x * TB + threadIdx.x;
    bool valid = i < N;
    int ii = valid ? i : (N - 1);
    int b = ii >> BSH, l = ii & (BNODES - 1);
    int J = 1 << Jlg;
    float t2 = 0.0f;
    for (int j = 0; j < J; ++j)
        t2 += __builtin_nontemporal_load(&pT[(size_t)((b << Jlg) + j) * BNODES + l]);
    float x = valid ? t2 * isiA[ii] : 0.0f;
    int g = graph_ids[ii];
    int g0 = __shfl(g, 0, 64);
    bool uniform = __all((!valid) || (g == g0));
    if (uniform) {
#pragma unroll
        for (int off = 32; off >= 1; off >>= 1) x += __shfl_down(x, off, 64);
        if ((threadIdx.x & 63) == 0) atomicAdd(&Xsum[g0], x);
    } else if (valid) {
        atomicAdd(&Xsum[g], x);
    }
}

__global__ void final_kernel(const float* __restrict__ Xsum, const int* __restrict__ graph_ids,
                             const float* __restrict__ W1, const float* __restrict__ W2,
                             const float* __restrict__ Wlast,
                             float* __restrict__ out, int N, int GC) {
    int i = blockIdx.x * TB + threadIdx.x;
    if (i < GC) {
        int g = i >> 3, j = i & 7;
        int lo = 0, hi = N;
        while (lo < hi) { int m = (lo + hi) >> 1; if (graph_ids[m] < g) lo = m + 1; else hi = m; }
        int lo2 = lo, hi2 = N;
        while (lo2 < hi2) { int m = (lo2 + hi2) >> 1; if (graph_ids[m] < g + 1) lo2 = m + 1; else hi2 = m; }
        float c = (float)(lo2 - lo);
        float r = 0.0f;
#pragma unroll
        for (int cc = 0; cc < 8; ++cc) {
            float m = 0.0f;
#pragma unroll
            for (int k = 0; k < 8; ++k) m += fmaxf(W1[k], 0.0f) * W2[k * 8 + cc];
            r += fmaxf(m, 0.0f) * Wlast[cc * 8 + j];
        }
        out[i] = Xsum[g] / fmaxf(c, 1.0f) * r;
    }
}

// ---------------- fallback (atomic) path ----------------

__global__ void fb_deg_kernel(const int* __restrict__ src, const int* __restrict__ dst,
                              float* __restrict__ deg_out, float* __restrict__ deg_in, int E) {
    int i = blockIdx.x * TB + threadIdx.x;
    if (i < E) {
        atomicAdd(&deg_out[src[i]], 1.0f);
        atomicAdd(&deg_in[dst[i]], 1.0f);
    }
}

__global__ void fb_prep_kernel(const float* __restrict__ deg_in, const float* __restrict__ deg_out,
                               float* __restrict__ isi, float* __restrict__ iso,
                               float* __restrict__ h0s, int N) {
    int i = blockIdx.x * TB + threadIdx.x;
    if (i < N) {
        float di = deg_in[i], dn = deg_out[i];
        float a = 1.0f / sqrtf(fmaxf(di, 1.0f));
        float b = 1.0f / sqrtf(fmaxf(dn, 1.0f));
        isi[i] = a; iso[i] = b; h0s[i] = di * b;
    }
}

__global__ void fb_conv_kernel(const int* __restrict__ src, const int* __restrict__ dst,
                               const float* __restrict__ vals, float* __restrict__ t, int E) {
    int i = blockIdx.x * TB + threadIdx.x;
    if (i < E) atomicAdd(&t[dst[i]], vals[src[i]]);
}

__global__ void fb_mid_kernel(const float* __restrict__ agg1, const float* __restrict__ isi,
                              const float* __restrict__ iso, float* __restrict__ s, int N) {
    int i = blockIdx.x * TB + threadIdx.x;
    if (i < N) s[i] = agg1[i] * isi[i] * iso[i];
}

__global__ void fb_pool_kernel(const float* __restrict__ t2, const float* __restrict__ isi,
                               const int* __restrict__ graph_ids,
                               float* __restrict__ Xsum, float* __restrict__ counts, int N) {
    int i = blockIdx.x * TB + threadIdx.x;
    bool valid = i < N;
    int ii = valid ? i : (N - 1);
    float x = valid ? t2[ii] * isi[ii] : 0.0f;
    float cnt = valid ? 1.0f : 0.0f;
    int g = graph_ids[ii];
    int g0 = __shfl(g, 0, 64);
    bool uniform = __all((!valid) || (g == g0));
    if (uniform) {
#pragma unroll
        for (int off = 32; off >= 1; off >>= 1) {
            x += __shfl_down(x, off, 64);
            cnt += __shfl_down(cnt, off, 64);
        }
        if ((threadIdx.x & 63) == 0) { atomicAdd(&Xsum[g0], x); atomicAdd(&counts[g0], cnt); }
    } else if (valid) {
        atomicAdd(&Xsum[g], x); atomicAdd(&counts[g], 1.0f);
    }
}

__global__ void fb_final_kernel(const float* __restrict__ Xsum, const float* __restrict__ counts,
                                const float* __restrict__ W1, const float* __restrict__ W2,
                                const float* __restrict__ Wlast, float* __restrict__ out, int GC) {
    int i = blockIdx.x * TB + threadIdx.x;
    if (i < GC) {
        int g = i >> 3, j = i & 7;
        float r = 0.0f;
#pragma unroll
        for (int c = 0; c < 8; ++c) {
            float m = 0.0f;
#pragma unroll
            for (int k = 0; k < 8; ++k) m += fmaxf(W1[k], 0.0f) * W2[k * 8 + c];
            r += fmaxf(m, 0.0f) * Wlast[c * 8 + j];
        }
        out[i] = Xsum[g] / fmaxf(counts[g], 1.0f) * r;
    }
}

// ---------------- launch ----------------

extern "C" void kernel_launch(void* const* d_in, const int* in_sizes, int n_in,
                              void* d_out, int out_size, void* d_ws, size_t ws_size,
                              hipStream_t stream) {
    const float* W1        = (const float*)d_in[0];
    const float* W2        = (const float*)d_in[1];
    const float* Wlast     = (const float*)d_in[2];
    const int*   src       = (const int*)d_in[3];
    const int*   dst       = (const int*)d_in[4];
    const int*   graph_ids = (const int*)d_in[5];
    float* out = (float*)d_out;

    const int E = in_sizes[3];
    const int N = in_sizes[5];
    const int G = out_size / 8;

    int NB   = (N + BNODES - 1) >> BSH;
    int Npad = NB << BSH;
    int NCH  = (E + SCH - 1) / SCH;
    // Per-bucket capacity: mean + 8192 (~20 sigma for E=10M random), 512-aligned.
    unsigned CAP = (unsigned)(((E / (NB > 0 ? NB : 1)) + 8192 + 511) & ~511);

    // Pick largest J in {16,8,4,2,1} whose layout fits ws.
    int Jlg = 4;
    size_t req = 0;
    size_t o_dstP, o_srcP, o_curD, o_curS, o_part, o_pio, o_h0sar, o_isi, o_Xsum;
    for (;; --Jlg) {
        int J = 1 << Jlg;
        size_t off = 0;
        auto A = [&](size_t bytes) { size_t o = off; off = (off + bytes + 127) & ~(size_t)127; return o; };
        o_dstP  = A((size_t)NB * CAP * 4);
        o_srcP  = A((size_t)NB * CAP * 2);
        o_curD  = A((size_t)NB * CSTR * 4);
        o_curS  = A((size_t)NB * CSTR * 4);
        o_part  = A((size_t)NB * J * BNODES * 4);  // pDeg -> pC -> pT (aliased)
        o_pio   = A((size_t)Npad * 4);
        o_h0sar = A((size_t)Npad * 4);             // h0s -> sarr (aliased)
        o_isi   = A((size_t)Npad * 4);
        o_Xsum  = A((size_t)G * 4);
        req = off;
        if (req <= ws_size || Jlg == 0) break;
    }

    bool fast = (N <= (1 << 19)) && (NB <= MAXNB) && (ws_size >= req) && (E >= 1);

    char* bp = (char*)d_ws;

    if (fast) {
        unsigned*       dstP = (unsigned*)(bp + o_dstP);
        unsigned short* srcP = (unsigned short*)(bp + o_srcP);
        unsigned* curD = (unsigned*)(bp + o_curD);
        unsigned* curS = (unsigned*)(bp + o_curS);
        unsigned* pDeg = (unsigned*)(bp + o_part);
        float*    pC   = (float*)(bp + o_part);
        float*    pT   = (float*)(bp + o_part);
        float* pio  = (float*)(bp + o_pio);
        float* h0s  = (float*)(bp + o_h0sar);
        float* sarr = (float*)(bp + o_h0sar);
        float* isiA = (float*)(bp + o_isi);
        float* Xsum = (float*)(bp + o_Xsum);

        int gridNp = (Npad + TB - 1) / TB;
        int gridN  = (N + TB - 1) / TB;
        int J = 1 << Jlg;
        int gridI = (max(NB, G) + TB - 1) / TB;

        int NCH1 = (NCH + 1) / 2;
        int NCH2 = NCH - NCH1;

        init_kernel<<<gridI, TB, 0, stream>>>(curD, curS, Xsum, NB, CAP, G);
        scatter_sort_kernel<<<NCH1, STB, 0, stream>>>(src, dst, curD, curS, dstP, srcP, NB, E, 0);
        if (NCH2 > 0)
            scatter_sort_kernel<<<NCH2, STB, 0, stream>>>(src, dst, curD, curS, dstP, srcP, NB, E, NCH1);
        deghist_kernel<<<NB * J, DTB, 0, stream>>>(srcP, dstP, curS, curD, CAP, pDeg, Jlg);
        prep_kernel<<<gridNp, TB, 0, stream>>>(pDeg, pio, h0s, isiA, Jlg, Npad);
        wh_kernel<0><<<NB * J, DTB, 0, stream>>>(dstP, curD, CAP, h0s, pC, Jlg);
        mid_kernel<<<gridNp, TB, 0, stream>>>(pC, pio, sarr, Jlg, Npad);
        wh_kernel<1><<<NB * J, DTB, 0, stream>>>(dstP, curD, CAP, sarr, pT, Jlg);
        poolfinal_kernel<<<gridN, TB, 0, stream>>>(pT, isiA, graph_ids, Xsum, Jlg, N);
        final_kernel<<<(out_size + TB - 1) / TB, TB, 0, stream>>>(Xsum, graph_ids,
                                                                  W1, W2, Wlast, out, N, out_size);
    } else {
        float* ws = (float*)d_ws;
        size_t f = 0;
        auto FA = [&](size_t n) { size_t o = f; f += (n + 3) & ~(size_t)3; return o; };
        size_t f_degin  = FA(N);
        size_t f_degout = FA(N);
        size_t f_agg1   = FA(N);
        size_t f_t2     = FA(N);
        size_t f_Xsum   = FA(G);
        size_t f_cnt    = FA(G);
        size_t zf = f;
        size_t f_isi = FA(N);
        size_t f_iso = FA(N);
        size_t f_h0s = FA(N);
        size_t f_s   = FA(N);
        hipMemsetAsync(ws, 0, zf * sizeof(float), stream);
        int gridE = (E + TB - 1) / TB;
        int gridN = (N + TB - 1) / TB;
        int gridO = (out_size + TB - 1) / TB;
        fb_deg_kernel<<<gridE, TB, 0, stream>>>(src, dst, ws + f_degout, ws + f_degin, E);
        fb_prep_kernel<<<gridN, TB, 0, stream>>>(ws + f_degin, ws + f_degout,
                                                 ws + f_isi, ws + f_iso, ws + f_h0s, N);
        fb_conv_kernel<<<gridE, TB, 0, stream>>>(src, dst, ws + f_h0s, ws + f_agg1, E);
        fb_mid_kernel<<<gridN, TB, 0, stream>>>(ws + f_agg1, ws + f_isi, ws + f_iso, ws + f_s, N);
        fb_conv_kernel<<<gridE, TB, 0, stream>>>(src, dst, ws + f_s, ws + f_t2, E);
        fb_pool_kernel<<<gridN, TB, 0, stream>>>(ws + f_t2, ws + f_isi, graph_ids,
                                                 ws + f_Xsum, ws + f_cnt, N);
        fb_final_kernel<<<gridO, TB, 0, stream>>>(ws + f_Xsum, ws + f_cnt, W1, W2, Wlast,
                                                  out, out_size);
    }
}

// Round 5
// 368.142 us; speedup vs baseline: 2.9183x; 1.0311x over previous
//
#include <hip/hip_runtime.h>

// GCN rank-1 collapse + one-pass counting-sort bucket partition (R11b).
// R11 resubmission: R4 bench died with "MI355X container failed twice"
// (infra, no kernel verdict). Kernel re-audited: vector-load alignment ok
// (CAP 512-aligned), head/tail guards bounded (<=3), no sync changes.
// Theory unchanged: wh_kernel 62us x2 is latency-bound (HBM 12.6%, VALU
// 4.7%, bank-conflict 0, ~1 outstanding gather/thread). R11: 4-wide ILP in
// wh + deghist inner loops (uint4/uint2 edge loads, 4 independent table
// gathers, then 4 LDS atomics) to quadruple MLP; vectorized LDS zero/flush.
// No traffic change. If wh doesn't move -> L2-gather throughput-bound ->
// R12 = 2D (dst-block x src-block) partition.

#define TB 256
#define DTB 512
#define STB 512
#define BSH 13
#define BNODES 8192
#define MAXNB 64
#define SCH 4096
#define SCH4 (SCH / 4)
#define EPT 8
#define CSTR 16
#define INVB 0xFFFFFFFFu

typedef __attribute__((ext_vector_type(4))) int int4v;
typedef __attribute__((ext_vector_type(4))) unsigned uint4v;
typedef __attribute__((ext_vector_type(2))) unsigned uint2v;
typedef __attribute__((ext_vector_type(4))) float float4v;

__global__ void init_kernel(unsigned* __restrict__ curD, unsigned* __restrict__ curS,
                            float* __restrict__ Xsum, int NB, unsigned CAP, int G) {
    int i = blockIdx.x * TB + threadIdx.x;
    if (i < NB) { curD[i * CSTR] = (unsigned)i * CAP; curS[i * CSTR] = (unsigned)i * CAP; }
    if (i < G) Xsum[i] = 0.0f;
}

__global__ void scatter_sort_kernel(const int* __restrict__ src, const int* __restrict__ dst,
                                    unsigned* __restrict__ curD, unsigned* __restrict__ curS,
                                    unsigned* __restrict__ dstP, unsigned short* __restrict__ srcP,
                                    int NB, int E, int blk0) {
    __shared__ unsigned cntD[MAXNB], cntS[MAXNB];     // counts -> insert cursors
    __shared__ unsigned deltaD[MAXNB], deltaS[MAXNB]; // globalBase - localExclusive
    __shared__ unsigned totD_s, totS_s;
    __shared__ unsigned payD[SCH];
    __shared__ unsigned short valS[SCH];
    __shared__ unsigned char mapD[SCH], mapS[SCH];

    int tid = threadIdx.x;
    if (tid < MAXNB) { cntD[tid] = 0u; cntS[tid] = 0u; }
    __syncthreads();

    unsigned sA[EPT], dA[EPT], bD[EPT], bS[EPT];
    int blk = blockIdx.x + blk0;
#pragma unroll
    for (int v = 0; v < 2; ++v) {
        int q = blk * SCH4 + v * STB + tid;
        int be = q * 4;
        if (be + 3 < E) {
            int4v s4 = __builtin_nontemporal_load((const int4v*)src + q);
            int4v d4 = __builtin_nontemporal_load((const int4v*)dst + q);
#pragma unroll
            for (int k = 0; k < 4; ++k) {
                sA[v*4+k] = (unsigned)s4[k];
                dA[v*4+k] = (unsigned)d4[k];
                bD[v*4+k] = dA[v*4+k] >> BSH;
                bS[v*4+k] = sA[v*4+k] >> BSH;
            }
        } else {
#pragma unroll
            for (int k = 0; k < 4; ++k) {
                int j = be + k;
                if (j < E) {
                    sA[v*4+k] = (unsigned)src[j];
                    dA[v*4+k] = (unsigned)dst[j];
                    bD[v*4+k] = dA[v*4+k] >> BSH;
                    bS[v*4+k] = sA[v*4+k] >> BSH;
                } else {
                    bD[v*4+k] = INVB; bS[v*4+k] = INVB;
                    sA[v*4+k] = 0u; dA[v*4+k] = 0u;
                }
            }
        }
    }

#pragma unroll
    for (int k = 0; k < EPT; ++k) {
        if (bD[k] != INVB) {
            atomicAdd(&cntD[bD[k]], 1u);
            atomicAdd(&cntS[bS[k]], 1u);
        }
    }
    __syncthreads();

    int wv = tid >> 6, ln = tid & 63;
    if (wv == 0) {
        unsigned x = (ln < NB) ? cntD[ln] : 0u;
        unsigned inc = x;
#pragma unroll
        for (int o = 1; o < 64; o <<= 1) {
            unsigned y = __shfl_up(inc, o, 64);
            if (ln >= o) inc += y;
        }
        unsigned exc = inc - x;
        if (ln < NB) {
            unsigned gb = atomicAdd(&curD[ln * CSTR], x);   // exact reservation, 1 line/bucket
            deltaD[ln] = gb - exc;
            cntD[ln] = exc;                                 // insert cursor
        }
        if (ln == 63) totD_s = inc;
    } else if (wv == 1) {
        unsigned x = (ln < NB) ? cntS[ln] : 0u;
        unsigned inc = x;
#pragma unroll
        for (int o = 1; o < 64; o <<= 1) {
            unsigned y = __shfl_up(inc, o, 64);
            if (ln >= o) inc += y;
        }
        unsigned exc = inc - x;
        if (ln < NB) {
            unsigned gb = atomicAdd(&curS[ln * CSTR], x);
            deltaS[ln] = gb - exc;
            cntS[ln] = exc;
        }
        if (ln == 63) totS_s = inc;
    }
    __syncthreads();

#pragma unroll
    for (int k = 0; k < EPT; ++k) {
        if (bD[k] != INVB) {
            unsigned p = atomicAdd(&cntD[bD[k]], 1u);
            payD[p] = ((dA[k] & (BNODES - 1)) << 19) | sA[k];
            mapD[p] = (unsigned char)bD[k];
            unsigned p2 = atomicAdd(&cntS[bS[k]], 1u);
            valS[p2] = (unsigned short)(sA[k] & (BNODES - 1));
            mapS[p2] = (unsigned char)bS[k];
        }
    }
    __syncthreads();

    unsigned tD = totD_s, tS = totS_s;
    for (unsigned i = tid; i < tD; i += STB) {
        unsigned b = mapD[i];
        dstP[deltaD[b] + i] = payD[i];   // delta[b]+i = gBase + (i - exc[b])
    }
    for (unsigned i = tid; i < tS; i += STB) {
        unsigned b = mapS[i];
        srcP[deltaS[b] + i] = valS[i];
    }
}

// Packed degrees per sub-block: high16 = deg_in (dstP), low16 = deg_out (srcP).
__global__ void deghist_kernel(const unsigned short* __restrict__ srcP, const unsigned* __restrict__ dstP,
                               const unsigned* __restrict__ curS, const unsigned* __restrict__ curD,
                               unsigned CAP, unsigned* __restrict__ pDeg, int Jlg) {
    __shared__ unsigned h[BNODES];
    {
        uint4v* hv = (uint4v*)h;
        for (int t = threadIdx.x; t < BNODES / 4; t += DTB) hv[t] = (uint4v)0u;
    }
    __syncthreads();
    int b = blockIdx.x >> Jlg;
    int j = blockIdx.x & ((1 << Jlg) - 1);
    unsigned s0 = (unsigned)b * CAP;

    // deg_in from dstP (4-wide ILP)
    {
        unsigned cD = curD[b * CSTR] - s0;
        unsigned lo = (unsigned)(((unsigned long long)cD * (unsigned)j) >> Jlg);
        unsigned hi = (unsigned)(((unsigned long long)cD * (unsigned)(j + 1)) >> Jlg);
        unsigned i0 = (lo + 3u) & ~3u;
        unsigned i1 = hi & ~3u;
        if (i0 >= i1) {
            for (unsigned i = lo + threadIdx.x; i < hi; i += DTB)
                atomicAdd(&h[dstP[s0 + i] >> 19], 0x10000u);
        } else {
            if (threadIdx.x < i0 - lo)
                atomicAdd(&h[dstP[s0 + lo + threadIdx.x] >> 19], 0x10000u);
            const uint4v* qp = (const uint4v*)(dstP + s0);
            for (unsigned q = i0 / 4u + threadIdx.x; q < i1 / 4u; q += DTB) {
                uint4v e4 = qp[q];
                atomicAdd(&h[e4.x >> 19], 0x10000u);
                atomicAdd(&h[e4.y >> 19], 0x10000u);
                atomicAdd(&h[e4.z >> 19], 0x10000u);
                atomicAdd(&h[e4.w >> 19], 0x10000u);
            }
            if (threadIdx.x < hi - i1)
                atomicAdd(&h[dstP[s0 + i1 + threadIdx.x] >> 19], 0x10000u);
        }
    }
    // deg_out from srcP (4-wide ILP via 8B loads)
    {
        unsigned cS = curS[b * CSTR] - s0;
        unsigned lo = (unsigned)(((unsigned long long)cS * (unsigned)j) >> Jlg);
        unsigned hi = (unsigned)(((unsigned long long)cS * (unsigned)(j + 1)) >> Jlg);
        unsigned i0 = (lo + 3u) & ~3u;
        unsigned i1 = hi & ~3u;
        if (i0 >= i1) {
            for (unsigned i = lo + threadIdx.x; i < hi; i += DTB)
                atomicAdd(&h[__builtin_nontemporal_load(&srcP[s0 + i])], 1u);
        } else {
            if (threadIdx.x < i0 - lo)
                atomicAdd(&h[srcP[s0 + lo + threadIdx.x]], 1u);
            const uint2v* qp = (const uint2v*)(srcP + s0);
            for (unsigned q = i0 / 4u + threadIdx.x; q < i1 / 4u; q += DTB) {
                uint2v e2 = __builtin_nontemporal_load(qp + q);
                atomicAdd(&h[e2.x & 0xFFFFu], 1u);
                atomicAdd(&h[e2.x >> 16], 1u);
                atomicAdd(&h[e2.y & 0xFFFFu], 1u);
                atomicAdd(&h[e2.y >> 16], 1u);
            }
            if (threadIdx.x < hi - i1)
                atomicAdd(&h[srcP[s0 + i1 + threadIdx.x]], 1u);
        }
    }
    __syncthreads();
    uint4v* rowv = (uint4v*)(pDeg + (size_t)blockIdx.x * BNODES);
    uint4v* hv = (uint4v*)h;
    for (int t = threadIdx.x; t < BNODES / 4; t += DTB) rowv[t] = hv[t];
}

__global__ void prep_kernel(const unsigned* __restrict__ pDeg,
                            float* __restrict__ pio, float* __restrict__ h0s,
                            float* __restrict__ isiA, int Jlg, int Npad) {
    int i = blockIdx.x * TB + threadIdx.x;
    if (i >= Npad) return;
    int b = i >> BSH, l = i & (BNODES - 1);
    int J = 1 << Jlg;
    unsigned sum = 0;
    for (int j = 0; j < J; ++j)
        sum += __builtin_nontemporal_load(&pDeg[(size_t)((b << Jlg) + j) * BNODES + l]);
    float din = (float)(sum >> 16), dout = (float)(sum & 0xFFFFu);
    float a  = 1.0f / sqrtf(fmaxf(din, 1.0f));    // inv_sqrt_in
    float bo = 1.0f / sqrtf(fmaxf(dout, 1.0f));   // inv_sqrt_out
    pio[i]  = a * bo;
    h0s[i]  = din * bo;   // invalid pad nodes: din=0 -> 0, contribute nothing
    isiA[i] = a;
}

// Weighted histogram over dstP: h[dst_local] += table[src].
// LAST=1 marks the final consumer of dstP (nt-load).
template <int LAST>
__global__ void wh_kernel(const unsigned* __restrict__ dstP, const unsigned* __restrict__ curD,
                          unsigned CAP, const float* __restrict__ table,
                          float* __restrict__ pOut, int Jlg) {
    __shared__ float h[BNODES];
    {
        float4v* hv = (float4v*)h;
        for (int t = threadIdx.x; t < BNODES / 4; t += DTB) hv[t] = (float4v)0.0f;
    }
    __syncthreads();
    int b = blockIdx.x >> Jlg;
    int j = blockIdx.x & ((1 << Jlg) - 1);
    unsigned s0 = (unsigned)b * CAP;
    unsigned cD = curD[b * CSTR] - s0;
    unsigned lo = (unsigned)(((unsigned long long)cD * (unsigned)j) >> Jlg);
    unsigned hi = (unsigned)(((unsigned long long)cD * (unsigned)(j + 1)) >> Jlg);
    unsigned i0 = (lo + 3u) & ~3u;
    unsigned i1 = hi & ~3u;
    if (i0 >= i1) {
        for (unsigned i = lo + threadIdx.x; i < hi; i += DTB) {
            unsigned e = dstP[s0 + i];
            atomicAdd(&h[e >> 19], table[e & 0x7FFFFu]);
        }
    } else {
        if (threadIdx.x < i0 - lo) {
            unsigned e = dstP[s0 + lo + threadIdx.x];
            atomicAdd(&h[e >> 19], table[e & 0x7FFFFu]);
        }
        const uint4v* qp = (const uint4v*)(dstP + s0);
        for (unsigned q = i0 / 4u + threadIdx.x; q < i1 / 4u; q += DTB) {
            uint4v e4 = LAST ? __builtin_nontemporal_load(qp + q) : qp[q];
            float t0 = table[e4.x & 0x7FFFFu];
            float t1 = table[e4.y & 0x7FFFFu];
            float t2 = table[e4.z & 0x7FFFFu];
            float t3 = table[e4.w & 0x7FFFFu];
            atomicAdd(&h[e4.x >> 19], t0);
            atomicAdd(&h[e4.y >> 19], t1);
            atomicAdd(&h[e4.z >> 19], t2);
            atomicAdd(&h[e4.w >> 19], t3);
        }
        if (threadIdx.x < hi - i1) {
            unsigned e = dstP[s0 + i1 + threadIdx.x];
            atomicAdd(&h[e >> 19], table[e & 0x7FFFFu]);
        }
    }
    __syncthreads();
    float4v* rowv = (float4v*)(pOut + (size_t)blockIdx.x * BNODES);
    float4v* hv = (float4v*)h;
    for (int t = threadIdx.x; t < BNODES / 4; t += DTB) rowv[t] = hv[t];
}

__global__ void mid_kernel(const float* __restrict__ pC, const float* __restrict__ pio,
                           float* __restrict__ sarr, int Jlg, int Npad) {
    int i = blockIdx.x * TB + threadIdx.x;
    if (i >= Npad) return;
    int b = i >> BSH, l = i & (BNODES - 1);
    int J = 1 << Jlg;
    float t1 = 0.0f;
    for (int j = 0; j < J; ++j)
        t1 += __builtin_nontemporal_load(&pC[(size_t)((b << Jlg) + j) * BNODES + l]);
    sarr[i] = t1 * pio[i];   // normal store: sarr is wh2's random-read table, keep cached
}

__global__ void poolfinal_kernel(const float* __restrict__ pT, const float* __restrict__ isiA,
                                 const int* __restrict__ graph_ids,
                                 float* __restrict__ Xsum, int Jlg, int N) {
    int i = blockIdx.x * TB + threadIdx.x;
    bool valid = i < N;
    int ii = valid ? i : (N - 1);
    int b = ii >> BSH, l = ii & (BNODES - 1);
    int J = 1 << Jlg;
    float t2 = 0.0f;
    for (int j = 0; j < J; ++j)
        t2 += __builtin_nontemporal_load(&pT[(size_t)((b << Jlg) + j) * BNODES + l]);
    float x = valid ? t2 * isiA[ii] : 0.0f;
    int g = graph_ids[ii];
    int g0 = __shfl(g, 0, 64);
    bool uniform = __all((!valid) || (g == g0));
    if (uniform) {
#pragma unroll
        for (int off = 32; off >= 1; off >>= 1) x += __shfl_down(x, off, 64);
        if ((threadIdx.x & 63) == 0) atomicAdd(&Xsum[g0], x);
    } else if (valid) {
        atomicAdd(&Xsum[g], x);
    }
}

__global__ void final_kernel(const float* __restrict__ Xsum, const int* __restrict__ graph_ids,
                             const float* __restrict__ W1, const float* __restrict__ W2,
                             const float* __restrict__ Wlast,
                             float* __restrict__ out, int N, int GC) {
    int i = blockIdx.x * TB + threadIdx.x;
    if (i < GC) {
        int g = i >> 3, j = i & 7;
        int lo = 0, hi = N;
        while (lo < hi) { int m = (lo + hi) >> 1; if (graph_ids[m] < g) lo = m + 1; else hi = m; }
        int lo2 = lo, hi2 = N;
        while (lo2 < hi2) { int m = (lo2 + hi2) >> 1; if (graph_ids[m] < g + 1) lo2 = m + 1; else hi2 = m; }
        float c = (float)(lo2 - lo);
        float r = 0.0f;
#pragma unroll
        for (int cc = 0; cc < 8; ++cc) {
            float m = 0.0f;
#pragma unroll
            for (int k = 0; k < 8; ++k) m += fmaxf(W1[k], 0.0f) * W2[k * 8 + cc];
            r += fmaxf(m, 0.0f) * Wlast[cc * 8 + j];
        }
        out[i] = Xsum[g] / fmaxf(c, 1.0f) * r;
    }
}

// ---------------- fallback (atomic) path ----------------

__global__ void fb_deg_kernel(const int* __restrict__ src, const int* __restrict__ dst,
                              float* __restrict__ deg_out, float* __restrict__ deg_in, int E) {
    int i = blockIdx.x * TB + threadIdx.x;
    if (i < E) {
        atomicAdd(&deg_out[src[i]], 1.0f);
        atomicAdd(&deg_in[dst[i]], 1.0f);
    }
}

__global__ void fb_prep_kernel(const float* __restrict__ deg_in, const float* __restrict__ deg_out,
                               float* __restrict__ isi, float* __restrict__ iso,
                               float* __restrict__ h0s, int N) {
    int i = blockIdx.x * TB + threadIdx.x;
    if (i < N) {
        float di = deg_in[i], dn = deg_out[i];
        float a = 1.0f / sqrtf(fmaxf(di, 1.0f));
        float b = 1.0f / sqrtf(fmaxf(dn, 1.0f));
        isi[i] = a; iso[i] = b; h0s[i] = di * b;
    }
}

__global__ void fb_conv_kernel(const int* __restrict__ src, const int* __restrict__ dst,
                               const float* __restrict__ vals, float* __restrict__ t, int E) {
    int i = blockIdx.x * TB + threadIdx.x;
    if (i < E) atomicAdd(&t[dst[i]], vals[src[i]]);
}

__global__ void fb_mid_kernel(const float* __restrict__ agg1, const float* __restrict__ isi,
                              const float* __restrict__ iso, float* __restrict__ s, int N) {
    int i = blockIdx.x * TB + threadIdx.x;
    if (i < N) s[i] = agg1[i] * isi[i] * iso[i];
}

__global__ void fb_pool_kernel(const float* __restrict__ t2, const float* __restrict__ isi,
                               const int* __restrict__ graph_ids,
                               float* __restrict__ Xsum, float* __restrict__ counts, int N) {
    int i = blockIdx.x * TB + threadIdx.x;
    bool valid = i < N;
    int ii = valid ? i : (N - 1);
    float x = valid ? t2[ii] * isi[ii] : 0.0f;
    float cnt = valid ? 1.0f : 0.0f;
    int g = graph_ids[ii];
    int g0 = __shfl(g, 0, 64);
    bool uniform = __all((!valid) || (g == g0));
    if (uniform) {
#pragma unroll
        for (int off = 32; off >= 1; off >>= 1) {
            x += __shfl_down(x, off, 64);
            cnt += __shfl_down(cnt, off, 64);
        }
        if ((threadIdx.x & 63) == 0) { atomicAdd(&Xsum[g0], x); atomicAdd(&counts[g0], cnt); }
    } else if (valid) {
        atomicAdd(&Xsum[g], x); atomicAdd(&counts[g], 1.0f);
    }
}

__global__ void fb_final_kernel(const float* __restrict__ Xsum, const float* __restrict__ counts,
                                const float* __restrict__ W1, const float* __restrict__ W2,
                                const float* __restrict__ Wlast, float* __restrict__ out, int GC) {
    int i = blockIdx.x * TB + threadIdx.x;
    if (i < GC) {
        int g = i >> 3, j = i & 7;
        float r = 0.0f;
#pragma unroll
        for (int c = 0; c < 8; ++c) {
            float m = 0.0f;
#pragma unroll
            for (int k = 0; k < 8; ++k) m += fmaxf(W1[k], 0.0f) * W2[k * 8 + c];
            r += fmaxf(m, 0.0f) * Wlast[c * 8 + j];
        }
        out[i] = Xsum[g] / fmaxf(counts[g], 1.0f) * r;
    }
}

// ---------------- launch ----------------

extern "C" void kernel_launch(void* const* d_in, const int* in_sizes, int n_in,
                              void* d_out, int out_size, void* d_ws, size_t ws_size,
                              hipStream_t stream) {
    const float* W1        = (const float*)d_in[0];
    const float* W2        = (const float*)d_in[1];
    const float* Wlast     = (const float*)d_in[2];
    const int*   src       = (const int*)d_in[3];
    const int*   dst       = (const int*)d_in[4];
    const int*   graph_ids = (const int*)d_in[5];
    float* out = (float*)d_out;

    const int E = in_sizes[3];
    const int N = in_sizes[5];
    const int G = out_size / 8;

    int NB   = (N + BNODES - 1) >> BSH;
    int Npad = NB << BSH;
    int NCH  = (E + SCH - 1) / SCH;
    // Per-bucket capacity: mean + 8192 (~20 sigma for E=10M random), 512-aligned.
    unsigned CAP = (unsigned)(((E / (NB > 0 ? NB : 1)) + 8192 + 511) & ~511);

    // Pick largest J in {16,8,4,2,1} whose layout fits ws.
    int Jlg = 4;
    size_t req = 0;
    size_t o_dstP, o_srcP, o_curD, o_curS, o_part, o_pio, o_h0sar, o_isi, o_Xsum;
    for (;; --Jlg) {
        int J = 1 << Jlg;
        size_t off = 0;
        auto A = [&](size_t bytes) { size_t o = off; off = (off + bytes + 127) & ~(size_t)127; return o; };
        o_dstP  = A((size_t)NB * CAP * 4);
        o_srcP  = A((size_t)NB * CAP * 2);
        o_curD  = A((size_t)NB * CSTR * 4);
        o_curS  = A((size_t)NB * CSTR * 4);
        o_part  = A((size_t)NB * J * BNODES * 4);  // pDeg -> pC -> pT (aliased)
        o_pio   = A((size_t)Npad * 4);
        o_h0sar = A((size_t)Npad * 4);             // h0s -> sarr (aliased)
        o_isi   = A((size_t)Npad * 4);
        o_Xsum  = A((size_t)G * 4);
        req = off;
        if (req <= ws_size || Jlg == 0) break;
    }

    bool fast = (N <= (1 << 19)) && (NB <= MAXNB) && (ws_size >= req) && (E >= 1);

    char* bp = (char*)d_ws;

    if (fast) {
        unsigned*       dstP = (unsigned*)(bp + o_dstP);
        unsigned short* srcP = (unsigned short*)(bp + o_srcP);
        unsigned* curD = (unsigned*)(bp + o_curD);
        unsigned* curS = (unsigned*)(bp + o_curS);
        unsigned* pDeg = (unsigned*)(bp + o_part);
        float*    pC   = (float*)(bp + o_part);
        float*    pT   = (float*)(bp + o_part);
        float* pio  = (float*)(bp + o_pio);
        float* h0s  = (float*)(bp + o_h0sar);
        float* sarr = (float*)(bp + o_h0sar);
        float* isiA = (float*)(bp + o_isi);
        float* Xsum = (float*)(bp + o_Xsum);

        int gridNp = (Npad + TB - 1) / TB;
        int gridN  = (N + TB - 1) / TB;
        int J = 1 << Jlg;
        int gridI = (max(NB, G) + TB - 1) / TB;

        int NCH1 = (NCH + 1) / 2;
        int NCH2 = NCH - NCH1;

        init_kernel<<<gridI, TB, 0, stream>>>(curD, curS, Xsum, NB, CAP, G);
        scatter_sort_kernel<<<NCH1, STB, 0, stream>>>(src, dst, curD, curS, dstP, srcP, NB, E, 0);
        if (NCH2 > 0)
            scatter_sort_kernel<<<NCH2, STB, 0, stream>>>(src, dst, curD, curS, dstP, srcP, NB, E, NCH1);
        deghist_kernel<<<NB * J, DTB, 0, stream>>>(srcP, dstP, curS, curD, CAP, pDeg, Jlg);
        prep_kernel<<<gridNp, TB, 0, stream>>>(pDeg, pio, h0s, isiA, Jlg, Npad);
        wh_kernel<0><<<NB * J, DTB, 0, stream>>>(dstP, curD, CAP, h0s, pC, Jlg);
        mid_kernel<<<gridNp, TB, 0, stream>>>(pC, pio, sarr, Jlg, Npad);
        wh_kernel<1><<<NB * J, DTB, 0, stream>>>(dstP, curD, CAP, sarr, pT, Jlg);
        poolfinal_kernel<<<gridN, TB, 0, stream>>>(pT, isiA, graph_ids, Xsum, Jlg, N);
        final_kernel<<<(out_size + TB - 1) / TB, TB, 0, stream>>>(Xsum, graph_ids,
                                                                  W1, W2, Wlast, out, N, out_size);
    } else {
        float* ws = (float*)d_ws;
        size_t f = 0;
        auto FA = [&](size_t n) { size_t o = f; f += (n + 3) & ~(size_t)3; return o; };
        size_t f_degin  = FA(N);
        size_t f_degout = FA(N);
        size_t f_agg1   = FA(N);
        size_t f_t2     = FA(N);
        size_t f_Xsum   = FA(G);
        size_t f_cnt    = FA(G);
        size_t zf = f;
        size_t f_isi = FA(N);
        size_t f_iso = FA(N);
        size_t f_h0s = FA(N);
        size_t f_s   = FA(N);
        hipMemsetAsync(ws, 0, zf * sizeof(float), stream);
        int gridE = (E + TB - 1) / TB;
        int gridN = (N + TB - 1) / TB;
        int gridO = (out_size + TB - 1) / TB;
        fb_deg_kernel<<<gridE, TB, 0, stream>>>(src, dst, ws + f_degout, ws + f_degin, E);
        fb_prep_kernel<<<gridN, TB, 0, stream>>>(ws + f_degin, ws + f_degout,
                                                 ws + f_isi, ws + f_iso, ws + f_h0s, N);
        fb_conv_kernel<<<gridE, TB, 0, stream>>>(src, dst, ws + f_h0s, ws + f_agg1, E);
        fb_mid_kernel<<<gridN, TB, 0, stream>>>(ws + f_agg1, ws + f_isi, ws + f_iso, ws + f_s, N);
        fb_conv_kernel<<<gridE, TB, 0, stream>>>(src, dst, ws + f_s, ws + f_t2, E);
        fb_pool_kernel<<<gridN, TB, 0, stream>>>(ws + f_t2, ws + f_isi, graph_ids,
                                                 ws + f_Xsum, ws + f_cnt, N);
        fb_final_kernel<<<gridO, TB, 0, stream>>>(ws + f_Xsum, ws + f_cnt, W1, W2, Wlast,
                                                  out, out_size);
    }
}